// Round 3
// baseline (657.354 us; speedup 1.0000x reference)
//
#include <hip/hip_runtime.h>
#include <cfloat>
#include <cstdint>

// Problem constants (fixed by the reference: N=65536, D=256, K=4096)
constexpr int N  = 65536;
constexpr int D  = 256;
constexpr int K  = 4096;

typedef __attribute__((ext_vector_type(8))) _Float16 half8;          // fp16x8 MFMA frag
typedef __attribute__((ext_vector_type(8))) unsigned short ushort8;  // 16B vector
typedef __attribute__((ext_vector_type(4))) float floatx4;

__device__ __forceinline__ floatx4 mfma_f16(half8 a, half8 b, floatx4 c) {
    return __builtin_amdgcn_mfma_f32_16x16x32_f16(a, b, c, 0, 0, 0);
}

// async global->LDS, 16B per lane; LDS dest = uniform base + lane*16 (m97 semantics)
__device__ __forceinline__ void ld_lds16(void* lds, const void* g) {
    __builtin_amdgcn_global_load_lds(
        (const __attribute__((address_space(1))) unsigned int*)g,
        (__attribute__((address_space(3))) unsigned int*)lds, 16, 0, 0);
}

// ---------------- c2[k] = sum_d C[k][d]^2 (fallback path only) ----------------
__global__ void prep_c2(const float* __restrict__ C, float* __restrict__ c2) {
    int k = blockIdx.x;
    int l = threadIdx.x;
    const float4* row = (const float4*)(C + (size_t)k * D);
    float4 v = row[l];
    float s = v.x*v.x + v.y*v.y + v.z*v.z + v.w*v.w;
    #pragma unroll
    for (int m = 1; m < 64; m <<= 1) s += __shfl_xor(s, m);
    if (l == 0) c2[k] = s;
}

// -- fp32 -> fp16 (RTN), X and C in one launch; per-BLOCK sum(x^2) partials and
// fused c2 (sum of C row squares) -- no hot atomics anywhere.
// C is written in MFMA-fragment-tiled layout Cf so the assign kernel can load
// B fragments straight global->register, fully coalesced:
//   Cf flat ushort8 index = ((ct64*8 + dk)*4 + j)*64 + quad*16 + lr
//   where center c = 64*ct64 + 16*j + lr, depth d = 32*dk + 8*quad + e.
__global__ void convert_f16_both(const float* __restrict__ X, const float* __restrict__ C,
                                 unsigned short* __restrict__ Xh,
                                 unsigned short* __restrict__ Cf,
                                 float* __restrict__ xsq_part,
                                 float* __restrict__ c2) {
    __shared__ float red[4];
    int id = blockIdx.x * 256 + threadIdx.x;
    const int nX = N * D / 8;                     // first 8192 blocks are pure X
    bool isX = id < nX;
    const float* src;
    if (isX) { src = X; }
    else     { src = C; id -= nX; }
    const float4* s4 = (const float4*)src;
    float4 a = s4[2*id], b = s4[2*id+1];
    float xs[8] = {a.x,a.y,a.z,a.w,b.x,b.y,b.z,b.w};
    ushort8 h;
    float ps = 0.f;
    #pragma unroll
    for (int i = 0; i < 8; ++i) {
        union { _Float16 f; unsigned short u; } cv;
        cv.f = (_Float16)xs[i];
        h[i] = cv.u;
        ps += xs[i]*xs[i];
    }
    int t = threadIdx.x;
    if (isX) {
        ((ushort8*)Xh)[id] = h;
        // block-uniform branch: per-block partial of sum(x^2)
        #pragma unroll
        for (int m = 1; m < 64; m <<= 1) ps += __shfl_xor(ps, m);
        if ((t & 63) == 0) red[t >> 6] = ps;
        __syncthreads();
        if (t == 0) xsq_part[blockIdx.x] = (red[0] + red[1]) + (red[2] + red[3]);
    } else {
        // fragment-tiled scatter store (C is only 2 MB; coalescing here is cheap)
        int c    = id >> 5;                 // center row (32 ushort8 per row)
        int dk   = (id >> 2) & 7;           // depth chunk (32 f16)
        int quad = id & 3;                  // 8-f16 segment within chunk
        int flat = (((c >> 6) * 8 + dk) * 4 + ((c >> 4) & 3)) * 64 + quad * 16 + (c & 15);
        ((ushort8*)Cf)[flat] = h;
        // C rows: 32 consecutive threads cover one row (D=256 = 32*8)
        #pragma unroll
        for (int m = 1; m < 32; m <<= 1) ps += __shfl_xor(ps, m);
        if ((t & 31) == 0) c2[c] = ps;
    }
}

// ---------------- fp16 MFMA GEMM + fused top-2 argmin (barrier-free) ----------
// Grid (N/128, 4): blockIdx.y = kb picks a 1024-center K-slice.
// Wave tile: 32 rows x 64 cols (wave w owns rows 32w..32w+31); all 4 waves
// share ONE linear B stream (ct64 = kb*16 + e, e = 0..15), pB += 256 per chunk.
// A (128x256) staged ONCE via global_load_lds(16B) + ONE barrier; main loop has
// NO barriers and NO cross-wave deps. B frags load global->register (coalesced,
// identical addresses across waves -> L1 broadcast; Cf is 2 MB, L2-resident),
// 1-deep pipeline with alternating named sets B0/B1. A frags are single-set
// just-in-time ds_read_b128 (immediate offsets, inner 8-chunk body unrolled).
// Live set ~100 arch VGPR + 32 acc: acc[2][4]=32, top2=32, B0/B1=32 (fixes the
// round-2 spill: WRITE_SIZE 114 MB of scratch at acc[4][4]+64-deep top2).
// Top-2 state flushed per 512-center half (after e=7 and e=15) into the SAME
// 8-entry cand layout as the validated round-0 kernel: h = 2*kb + half.
// Score = c2[col] - 2*dot (x2 omitted: row-constant, argmin-invariant).
__global__ __launch_bounds__(256, 2) void mfma_assign(
        const unsigned short* __restrict__ Xh, const unsigned short* __restrict__ Cfu,
        const float* __restrict__ c2, float* __restrict__ cand)
{
    __shared__ __align__(16) unsigned short sA[8*128*4*8];   // 64 KB: (dk,row,slot)x8h

    const int t    = threadIdx.x;
    const int w    = t >> 6, l = t & 63;
    const int quad = l >> 4, lr = l & 15;
    const int rowbase = blockIdx.x * 128;
    const int kb   = blockIdx.y;                 // 0..3

    const int rl  = l >> 2;                      // staging local row (0..15)
    const int gsw = (l & 3) ^ ((l >> 3) & 3);    // swizzled depth-group to fetch

    // ---- stage A: all 8 depth-chunks (64 calls, 16 per wave) ----
    #pragma unroll
    for (int k = 0; k < 16; ++k) {
        int q = w*16 + k;                                      // 0..63
        int c = q >> 3, rb = (q & 7) * 16;
        const unsigned short* gp = Xh + (size_t)(rowbase + rb + rl)*D + c*32 + gsw*8;
        ld_lds16((char*)sA + q*1024, gp);
    }

    // B fragment stream: flat(ct64,dk,j,l) = ((ct64*8+dk)*4 + j)*64 + l (ushort8).
    // kb slice = ct64 in [kb*16, kb*16+16) -> contiguous 512 KB, linear walk.
    const half8* pB = (const half8*)Cfu + (size_t)kb*32768 + l;
    const char* sAc = (const char*)sA;
    // frag-read byte offset (swizzle: slot = quad ^ ((lr>>1)&3); 2-way banks = free)
    const int sA_off = ((32*w + lr)*4 + (quad ^ ((lr>>1)&3)))*16;

    half8 B0[4], B1[4];
    floatx4 acc[2][4];
    float c2v[4]; int jidx[4];
    // per-lane running top-2 per owned row (8 rows: st = 4*i + r)
    float v1[8], v2[8]; int x1[8], x2s[8];

#define LOADB(Bs) do {                                                   \
        Bs[0] = pB[0]; Bs[1] = pB[64]; Bs[2] = pB[128]; Bs[3] = pB[192]; \
        pB += 256; } while (0)

#define STEP(dk, Bc) do {                                                \
        half8 Af0 = *(const half8*)(sAc + (dk)*8192 + 0*1024 + sA_off);  \
        half8 Af1 = *(const half8*)(sAc + (dk)*8192 + 1*1024 + sA_off);  \
        _Pragma("unroll")                                                \
        for (int j_ = 0; j_ < 4; ++j_) {                                 \
            acc[0][j_] = mfma_f16(Af0, Bc[j_], acc[0][j_]);              \
            acc[1][j_] = mfma_f16(Af1, Bc[j_], acc[1][j_]);              \
        } } while (0)

// cross-lane (16 lr lanes) top-2 butterfly per owned row, write entry h, reinit
#define FLUSH(h) do {                                                       \
    _Pragma("unroll")                                                       \
    for (int i = 0; i < 2; ++i)                                             \
        _Pragma("unroll")                                                   \
        for (int r = 0; r < 4; ++r) {                                       \
            int st = 4*i + r;                                               \
            float a1 = v1[st], a2 = v2[st]; int ax1 = x1[st], ax2 = x2s[st];\
            _Pragma("unroll")                                               \
            for (int m = 1; m < 16; m <<= 1) {                              \
                float b1f = __shfl_xor(a1, m); int bx1 = __shfl_xor(ax1, m);\
                float b2f = __shfl_xor(a2, m); int bx2 = __shfl_xor(ax2, m);\
                bool tt = (b1f < a1) || (b1f == a1 && bx1 < ax1);           \
                float n1 = tt ? b1f : a1; int nx1 = tt ? bx1 : ax1;         \
                float w1 = tt ? a1 : b1f; int wx1 = tt ? ax1 : bx1;         \
                float w2 = tt ? b2f : a2; int wx2 = tt ? bx2 : ax2;         \
                bool uu = (w2 < w1) || (w2 == w1 && wx2 < wx1);             \
                a1 = n1; ax1 = nx1;                                         \
                a2 = uu ? w2 : w1; ax2 = uu ? wx2 : wx1;                    \
            }                                                               \
            if (lr == 0) {                                                  \
                int row = rowbase + 32*w + 16*i + 4*quad + r;               \
                float4 o; o.x = a1; o.y = __int_as_float(ax1);              \
                o.z = a2; o.w = __int_as_float(ax2);                        \
                ((float4*)cand)[(size_t)row*8 + (h)] = o;                   \
            }                                                               \
            v1[st] = FLT_MAX; v2[st] = FLT_MAX;                             \
            x1[st] = 0x7fffffff; x2s[st] = 0x7fffffff;                      \
        } } while (0)

    // prologue: chunk 0's B in flight before the single staging barrier
    LOADB(B0);
    __syncthreads();        // drains sA staging (B0 too -- prologue only)

    #pragma unroll
    for (int i = 0; i < 8; ++i) { v1[i]=FLT_MAX; v2[i]=FLT_MAX; x1[i]=0x7fffffff; x2s[i]=0x7fffffff; }

    for (int half = 0; half < 2; ++half) {
        for (int e8 = 0; e8 < 8; ++e8) {
            const int ct64 = kb*16 + half*8 + e8;
            #pragma unroll
            for (int i = 0; i < 2; ++i)
                #pragma unroll
                for (int j = 0; j < 4; ++j) acc[i][j] = (floatx4)0.f;
            #pragma unroll
            for (int j = 0; j < 4; ++j) {
                int col = ct64*64 + 16*j + lr;
                c2v[j] = c2[col]; jidx[j] = col;
            }

            // 8 chunks, 1-deep pipeline, alternating B sets (parity resets per
            // epoch since 8 is even). Last issued load of the kernel overreads
            // <5 KB past the kb slice -- covered by workspace, never consumed.
            LOADB(B1); STEP(0, B0);
            LOADB(B0); STEP(1, B1);
            LOADB(B1); STEP(2, B0);
            LOADB(B0); STEP(3, B1);
            LOADB(B1); STEP(4, B0);
            LOADB(B0); STEP(5, B1);
            LOADB(B1); STEP(6, B0);
            LOADB(B0); STEP(7, B1);

            // fused top-2 merge: rows st=4i+r (row=32w+16i+4quad+r), cols jidx[j]
            #pragma unroll
            for (int i = 0; i < 2; ++i)
                #pragma unroll
                for (int j = 0; j < 4; ++j)
                    #pragma unroll
                    for (int r = 0; r < 4; ++r) {
                        float s = fmaf(-2.f, acc[i][j][r], c2v[j]);
                        int st = 4*i + r;
                        bool cA = s < v1[st];
                        bool cB = s < v2[st];
                        float tv = cB ? s : v2[st]; int tx = cB ? jidx[j] : x2s[st];
                        v2[st] = cA ? v1[st] : tv;  x2s[st] = cA ? x1[st] : tx;
                        v1[st] = cA ? s : v1[st];   x1[st]  = cA ? jidx[j] : x1[st];
                    }
        }
        FLUSH(2*kb + half);
    }

#undef LOADB
#undef STEP
#undef FLUSH
}

// ------- margin-gated exact recheck + labels + histogram, 4 rows per wave ------
// Lanes split into 4 groups of 16; group g owns row 4*waverow+g. One butterfly
// serves all 4 rows. Certain groups (margin > 0.25) write immediately with no
// memory traffic; uncertain rows (rare) are handled whole-wave sequentially.
__global__ __launch_bounds__(256) void recheck_label(
        const float* __restrict__ X, const float* __restrict__ C,
        const float* __restrict__ c2, const float* __restrict__ cand,
        float* __restrict__ out_labels, int* __restrict__ labInt,
        int* __restrict__ cnt)
{
    int t = threadIdx.x, w = t >> 6, l = t & 63;
    int g  = l >> 4;                       // row-group within wave
    int lr = l & 15;
    int row0 = (blockIdx.x * 4 + w) * 4;   // 4 rows per wave
    int row  = row0 + g;

    // lane lr of group g holds candidate lr of its row
    float4 e = ((const float4*)cand)[(size_t)row*8 + (lr >> 1)];
    float s  = (lr & 1) ? e.z : e.x;
    int  idx = (lr & 1) ? __float_as_int(e.w) : __float_as_int(e.y);

    // top-2 butterfly within each 16-lane group (all lanes end with group result)
    float a1 = s, a2 = FLT_MAX; int ax1 = idx, ax2 = 0x7fffffff;
    #pragma unroll
    for (int m = 1; m < 16; m <<= 1) {
        float b1 = __shfl_xor(a1, m); int bx1 = __shfl_xor(ax1, m);
        float b2 = __shfl_xor(a2, m); int bx2 = __shfl_xor(ax2, m);
        bool tt = (b1 < a1) || (b1 == a1 && bx1 < ax1);
        float n1 = tt ? b1 : a1; int nx1 = tt ? bx1 : ax1;
        float w1 = tt ? a1 : b1; int wx1 = tt ? ax1 : bx1;
        float w2 = tt ? b2 : a2; int wx2 = tt ? bx2 : ax2;
        bool uu = (w2 < w1) || (w2 == w1 && wx2 < wx1);
        a1 = n1; ax1 = nx1;
        a2 = uu ? w2 : w1; ax2 = uu ? wx2 : wx1;
    }

    bool certain = (a2 - a1 > 0.25f);               // group-uniform
    unsigned long long certMask = __ballot(certain);

    // fast path: certain groups store now (no X/C traffic)
    if (certain && lr == 0) {
        out_labels[row] = (float)ax1;
        labInt[row] = ax1;
        atomicAdd(&cnt[ax1], 1);
    }

    // slow path: whole wave processes each uncertain row sequentially
    #pragma unroll
    for (int q = 0; q < 4; ++q) {
        if ((certMask >> (q*16)) & 1ull) continue;   // wave-uniform test
        int r = row0 + q;
        float sq  = __shfl(s,   q*16 + lr);          // group q's candidates -> lanes 0..15
        int   iq  = __shfl(idx, q*16 + lr);
        float gs1 = __shfl(a1,  q*16);

        float4 xv = ((const float4*)X)[(size_t)r*64 + l];
        float px = xv.x*xv.x + xv.y*xv.y + xv.z*xv.z + xv.w*xv.w;
        #pragma unroll
        for (int m = 1; m < 64; m <<= 1) px += __shfl_xor(px, m);

        bool active = (l < 16) && (sq <= gs1 + 0.25f);
        unsigned long long mask = __ballot(active);
        float best = FLT_MAX; int bi = 0x7fffffff;
        while (mask) {
            int k = __ffsll((long long)mask) - 1;
            mask &= mask - 1;
            int ck = __shfl(iq, k);
            float4 cv = ((const float4*)C)[(size_t)ck*64 + l];
            float pd = xv.x*cv.x + xv.y*cv.y + xv.z*cv.z + xv.w*cv.w;
            #pragma unroll
            for (int m = 1; m < 64; m <<= 1) pd += __shfl_xor(pd, m);
            float d2 = fmaf(-2.f, pd, px) + c2[ck];   // numpy's rounding order
            if (d2 < best || (d2 == best && ck < bi)) { best = d2; bi = ck; }
        }
        if (l == 0) {
            out_labels[r] = (float)bi;
            labInt[r] = bi;
            atomicAdd(&cnt[bi], 1);
        }
    }
}

// ---------------- exclusive prefix sum of the 4096-bin histogram -------------
__global__ void prefix_kernel(const int* __restrict__ cnt,
                              int* __restrict__ offs, int* __restrict__ cursor) {
    int l = threadIdx.x;                 // 64 lanes, 64 bins each
    int s = 0;
    #pragma unroll 8
    for (int i = 0; i < 64; ++i) s += cnt[l*64 + i];
    int inc = s;
    #pragma unroll
    for (int off = 1; off < 64; off <<= 1) {
        int u = __shfl_up(inc, off);
        if (l >= off) inc += u;
    }
    int run = inc - s;                   // exclusive lane base
    for (int i = 0; i < 64; ++i) {
        int k = l*64 + i;
        offs[k] = run; cursor[k] = run;
        run += cnt[k];
    }
}

// ---------------- bucket rows by label (one position atomic per row) ---------
__global__ void scatter_idx(const int* __restrict__ labInt,
                            int* __restrict__ cursor, int* __restrict__ sortedIdx) {
    int i = blockIdx.x * 256 + threadIdx.x;
    int lab = labInt[i];
    int pos = atomicAdd(&cursor[lab], 1);
    sortedIdx[pos] = i;
}

// -- atomic-free segment sum (block per center) + finalize + loss term store --
// loss = sum(x^2) [xsq_part] + sum_k (m_k*|c_k|^2 - 2*c_k.seg_k) [lossC, here]
__global__ __launch_bounds__(256) void center_update(
        const float* __restrict__ X, const float* __restrict__ C,
        const int* __restrict__ counts0, const int* __restrict__ cnt,
        const int* __restrict__ offs, const int* __restrict__ sortedIdx,
        float* __restrict__ lossC, float* __restrict__ out)
{
    __shared__ float red[4];
    int k = blockIdx.x, d = threadIdx.x;   // d = dim (D == 256 == blockDim)
    int start = offs[k], m = cnt[k];
    float acc = 0.f;
    int i = 0;
    for (; i + 4 <= m; i += 4) {
        int r0 = sortedIdx[start+i],   r1 = sortedIdx[start+i+1];
        int r2 = sortedIdx[start+i+2], r3 = sortedIdx[start+i+3];
        float a0 = X[(size_t)r0*D + d], a1 = X[(size_t)r1*D + d];
        float a2 = X[(size_t)r2*D + d], a3 = X[(size_t)r3*D + d];
        acc += (a0 + a1) + (a2 + a3);
    }
    for (; i < m; ++i) acc += X[(size_t)sortedIdx[start+i]*D + d];

    float cv = C[(size_t)k*D + d];
    float c0 = (float)counts0[k];
    out[N + (size_t)k*D + d] = (c0 * cv + acc) / (c0 + (float)m);
    if (d == 0) out[N + (size_t)K*D + k] = (float)(counts0[k] + m);

    // loss center-term: cv*(m*cv - 2*acc), reduced over d, plain store (no atomic)
    float lp = cv * fmaf((float)m, cv, -2.f*acc);
    #pragma unroll
    for (int s = 1; s < 64; s <<= 1) lp += __shfl_xor(lp, s);
    if ((d & 63) == 0) red[d >> 6] = lp;
    __syncthreads();
    if (d == 0) lossC[k] = (red[0] + red[1]) + (red[2] + red[3]);
}

// ---------------- final loss: reduce 8192 xsq partials + 4096 center terms ----
__global__ __launch_bounds__(256) void loss_final(
        const float* __restrict__ xsq_part, const float* __restrict__ lossC,
        float* __restrict__ out)
{
    __shared__ double red[4];
    int t = threadIdx.x;
    double s = 0.0;
    for (int i = t; i < 8192; i += 256) s += (double)xsq_part[i];
    for (int i = t; i < 4096; i += 256) s += (double)lossC[i];
    #pragma unroll
    for (int m = 1; m < 64; m <<= 1) s += __shfl_xor(s, m);
    if ((t & 63) == 0) red[t >> 6] = s;
    __syncthreads();
    if (t == 0)
        out[N + (size_t)K*D + K] = (float)(((red[0] + red[1]) + (red[2] + red[3])) / (double)N);
}

// ---------------- finalize (fallback path only) ----------------
__global__ void finalize_kernel(const float* __restrict__ C,
                                const int* __restrict__ counts0,
                                const float* __restrict__ seg,
                                const int* __restrict__ cnt,
                                const double* __restrict__ lossAcc,
                                float* __restrict__ out)
{
    int g = blockIdx.x * 256 + threadIdx.x;   // 0 .. K*D-1
    int k = g >> 8;                           // D = 256
    float c0 = (float)counts0[k];
    float m  = (float)cnt[k];
    out[N + g] = (c0 * C[g] + seg[g]) / (c0 + m);
    if (g < K) out[N + (size_t)K*D + g] = (float)(counts0[g] + cnt[g]);
    if (g == 0) out[N + (size_t)K*D + K] = (float)(lossAcc[0] / (double)N);
}

// ================= fallback (round-1 proven fp32 path, small ws) =============
__global__ __launch_bounds__(256, 2) void assign_fp32(
        const float* __restrict__ X, const float* __restrict__ C,
        const float* __restrict__ c2, float* __restrict__ out_labels,
        float* __restrict__ seg, int* __restrict__ cnt,
        double* __restrict__ lossAcc)
{
    constexpr int BM = 128, BN = 128, KD = 16;
    __shared__ float As[KD][BM];
    __shared__ float Bs[KD][BN];
    __shared__ float x2f[BM];
    __shared__ int   labs[BM];

    const int t  = threadIdx.x;
    const int tx = t & 15;
    const int ty = t >> 4;
    const int rowbase = blockIdx.x * BM;

    {
        int r  = t >> 1;
        int dh = (t & 1) * (D / 2);
        const float4* xr = (const float4*)(X + (size_t)(rowbase + r) * D + dh);
        float s = 0.f;
        #pragma unroll
        for (int i = 0; i < D / 8; ++i) {
            float4 v = xr[i];
            s += v.x*v.x + v.y*v.y + v.z*v.z + v.w*v.w;
        }
        s += __shfl_xor(s, 1);
        if ((t & 1) == 0) x2f[r] = s;
    }
    __syncthreads();

    float x2v[8];
    #pragma unroll
    for (int i = 0; i < 4; ++i) { x2v[i] = x2f[4*ty + i]; x2v[i+4] = x2f[64 + 4*ty + i]; }

    float rmv[8]; int rmi[8];
    #pragma unroll
    for (int i = 0; i < 8; ++i) { rmv[i] = FLT_MAX; rmi[i] = 0x7fffffff; }

    for (int ct = 0; ct < K / BN; ++ct) {
        float acc[8][8];
        #pragma unroll
        for (int i = 0; i < 8; ++i)
            #pragma unroll
            for (int j = 0; j < 8; ++j) acc[i][j] = 0.f;

        float c2f2[8];
        {
            float4 a = *(const float4*)(c2 + ct*BN + 4*tx);
            float4 b = *(const float4*)(c2 + ct*BN + 64 + 4*tx);
            c2f2[0]=a.x; c2f2[1]=a.y; c2f2[2]=a.z; c2f2[3]=a.w;
            c2f2[4]=b.x; c2f2[5]=b.y; c2f2[6]=b.z; c2f2[7]=b.w;
        }

        for (int dk = 0; dk < D / KD; ++dk) {
            #pragma unroll
            for (int i = 0; i < 2; ++i) {
                int f  = t + 256 * i;
                int r  = f >> 2;
                int dp = f & 3;
                float4 av = *(const float4*)(X + (size_t)(rowbase + r) * D + dk*KD + 4*dp);
                float4 bv = *(const float4*)(C + (size_t)(ct*BN + r) * D + dk*KD + 4*dp);
                As[4*dp+0][r]=av.x; As[4*dp+1][r]=av.y; As[4*dp+2][r]=av.z; As[4*dp+3][r]=av.w;
                Bs[4*dp+0][r]=bv.x; Bs[4*dp+1][r]=bv.y; Bs[4*dp+2][r]=bv.z; Bs[4*dp+3][r]=bv.w;
            }
            __syncthreads();
            #pragma unroll
            for (int kk = 0; kk < KD; ++kk) {
                float4 a0 = *(const float4*)&As[kk][4*ty];
                float4 a1 = *(const float4*)&As[kk][64 + 4*ty];
                float4 b0 = *(const float4*)&Bs[kk][4*tx];
                float4 b1 = *(const float4*)&Bs[kk][64 + 4*tx];
                float av[8] = {a0.x,a0.y,a0.z,a0.w,a1.x,a1.y,a1.z,a1.w};
                float bv[8] = {b0.x,b0.y,b0.z,b0.w,b1.x,b1.y,b1.z,b1.w};
                #pragma unroll
                for (int i = 0; i < 8; ++i)
                    #pragma unroll
                    for (int j = 0; j < 8; ++j)
                        acc[i][j] = fmaf(av[i], bv[j], acc[i][j]);
            }
            __syncthreads();
        }

        #pragma unroll
        for (int i = 0; i < 8; ++i) {
            float bv = FLT_MAX; int bi = 0x7fffffff;
            #pragma unroll
            for (int j = 0; j < 8; ++j) {
                int coll = (j < 4) ? (4*tx + j) : (64 + 4*tx + (j - 4));
                float v = fmaf(-2.f, acc[i][j], x2v[i]) + c2f2[j];
                int idx = ct * BN + coll;
                if (v < bv || (v == bv && idx < bi)) { bv = v; bi = idx; }
            }
            #pragma unroll
            for (int m = 1; m < 16; m <<= 1) {
                float ov = __shfl_xor(bv, m);
                int   oi = __shfl_xor(bi, m);
                if (ov < bv || (ov == bv && oi < bi)) { bv = ov; bi = oi; }
            }
            if (bv < rmv[i] || (bv == rmv[i] && bi < rmi[i])) { rmv[i] = bv; rmi[i] = bi; }
        }
    }

    if (tx == 0) {
        #pragma unroll
        for (int i = 0; i < 8; ++i) {
            int r = (i < 4) ? (4*ty + i) : (64 + 4*ty + (i - 4));
            labs[r] = rmi[i];
            out_labels[rowbase + r] = (float)rmi[i];
            atomicAdd(&cnt[rmi[i]], 1);
        }
    }
    __syncthreads();

    {
        int r   = t >> 1;
        int dh  = (t & 1) * (D / 2);
        int lab = labs[r];
        const float4* xr = (const float4*)(X + (size_t)(rowbase + r) * D + dh);
        const float4* cr = (const float4*)(C + (size_t)lab * D + dh);
        float* sp = seg + (size_t)lab * D + dh;
        float ls = 0.f;
        #pragma unroll 8
        for (int i = 0; i < D / 8; ++i) {
            float4 xv = xr[i];
            float4 cv = cr[i];
            atomicAdd(sp + 4*i + 0, xv.x);
            atomicAdd(sp + 4*i + 1, xv.y);
            atomicAdd(sp + 4*i + 2, xv.z);
            atomicAdd(sp + 4*i + 3, xv.w);
            float d0 = xv.x - cv.x, d1 = xv.y - cv.y;
            float d2 = xv.z - cv.z, d3 = xv.w - cv.w;
            ls += d0*d0 + d1*d1 + d2*d2 + d3*d3;
        }
        #pragma unroll
        for (int m = 1; m < 64; m <<= 1) ls += __shfl_xor(ls, m);
        if ((t & 63) == 0) atomicAdd(lossAcc, (double)ls);
    }
}

extern "C" void kernel_launch(void* const* d_in, const int* in_sizes, int n_in,
                              void* d_out, int out_size, void* d_ws, size_t ws_size,
                              hipStream_t stream) {
    const float* X       = (const float*)d_in[0];   // [N, D]
    const float* C       = (const float*)d_in[1];   // [K, D]
    const int*   counts0 = (const int*)d_in[2];     // [K]
    float* out = (float*)d_out;

    // workspace layout
    char* p = (char*)d_ws;
    float*  seg     = (float*)p;          p += (size_t)K * D * 4;   // 4 MB (fallback / sort scratch)
    int*    cnt     = (int*)p;            p += (size_t)K * 4;       // 16 KB
    float*  c2      = (float*)p;          p += (size_t)K * 4;       // 16 KB
    double* lossAcc = (double*)p;         p += 16;
    size_t zero_all = (size_t)(p - (char*)d_ws);
    float*  cand    = (float*)p;          p += (size_t)N * 32 * 4;  // 8 MB (16 cands/row)
    unsigned short* Xh = (unsigned short*)p; p += (size_t)N * D * 2; // 32 MB
    unsigned short* Cf = (unsigned short*)p; p += (size_t)K * D * 2; //  2 MB (frag-tiled)
    float* xsq_part = (float*)p;          p += 8192 * 4;            // 32 KB (also pads Cf overread)
    float* lossC    = (float*)p;          p += (size_t)K * 4;       // 16 KB (also pads Cf overread)
    size_t need = (size_t)(p - (char*)d_ws);                        // ~46 MB

    // sort scratch reuses the seg region (mfma path never touches seg)
    int* labInt    = (int*)seg;                  // N ints
    int* sortedIdx = labInt + N;                 // N ints
    int* offs      = sortedIdx + N;              // K ints
    int* cursor    = offs + K;                   // K ints

    if (ws_size >= need) {
        hipMemsetAsync(cnt, 0, (size_t)K * 4, stream);  // histogram only
        convert_f16_both<<<(N*D/8 + K*D/8)/256, 256, 0, stream>>>(X, C, Xh, Cf, xsq_part, c2);
        mfma_assign<<<dim3(N/128, 4), 256, 0, stream>>>(Xh, Cf, c2, cand);
        recheck_label<<<N/16, 256, 0, stream>>>(X, C, c2, cand, out, labInt, cnt);
        prefix_kernel<<<1, 64, 0, stream>>>(cnt, offs, cursor);
        scatter_idx<<<N/256, 256, 0, stream>>>(labInt, cursor, sortedIdx);
        center_update<<<K, 256, 0, stream>>>(X, C, counts0, cnt, offs, sortedIdx, lossC, out);
        loss_final<<<1, 256, 0, stream>>>(xsq_part, lossC, out);
    } else {
        hipMemsetAsync(d_ws, 0, zero_all, stream);
        prep_c2<<<K, 64, 0, stream>>>(C, c2);
        assign_fp32<<<N/128, 256, 0, stream>>>(X, C, c2, out, seg, cnt, lossAcc);
        finalize_kernel<<<(K*D)/256, 256, 0, stream>>>(C, counts0, seg, cnt, lossAcc, out);
    }
}

// Round 4
// 651.912 us; speedup vs baseline: 1.0083x; 1.0083x over previous
//
#include <hip/hip_runtime.h>
#include <cfloat>
#include <cstdint>

// Problem constants (fixed by the reference: N=65536, D=256, K=4096)
constexpr int N  = 65536;
constexpr int D  = 256;
constexpr int K  = 4096;

typedef __attribute__((ext_vector_type(8))) _Float16 half8;          // fp16x8 MFMA frag
typedef __attribute__((ext_vector_type(8))) unsigned short ushort8;  // 16B vector
typedef __attribute__((ext_vector_type(4))) float floatx4;

__device__ __forceinline__ floatx4 mfma_f16(half8 a, half8 b, floatx4 c) {
    return __builtin_amdgcn_mfma_f32_16x16x32_f16(a, b, c, 0, 0, 0);
}

// async global->LDS, 16B per lane; LDS dest = uniform base + lane*16 (m97 semantics)
__device__ __forceinline__ void ld_lds16(void* lds, const void* g) {
    __builtin_amdgcn_global_load_lds(
        (const __attribute__((address_space(1))) unsigned int*)g,
        (__attribute__((address_space(3))) unsigned int*)lds, 16, 0, 0);
}

// ---------------- c2[k] = sum_d C[k][d]^2 (fallback path only) ----------------
__global__ void prep_c2(const float* __restrict__ C, float* __restrict__ c2) {
    int k = blockIdx.x;
    int l = threadIdx.x;
    const float4* row = (const float4*)(C + (size_t)k * D);
    float4 v = row[l];
    float s = v.x*v.x + v.y*v.y + v.z*v.z + v.w*v.w;
    #pragma unroll
    for (int m = 1; m < 64; m <<= 1) s += __shfl_xor(s, m);
    if (l == 0) c2[k] = s;
}

// -- fp32 -> fp16 (RTN), X and C in one launch; per-BLOCK sum(x^2) partials and
// fused c2 (sum of C row squares) -- no hot atomics anywhere. Ch is row-major.
__global__ void convert_f16_both(const float* __restrict__ X, const float* __restrict__ C,
                                 unsigned short* __restrict__ Xh,
                                 unsigned short* __restrict__ Ch,
                                 float* __restrict__ xsq_part,
                                 float* __restrict__ c2) {
    __shared__ float red[4];
    int id = blockIdx.x * 256 + threadIdx.x;
    const int nX = N * D / 8;                     // first 8192 blocks are pure X
    bool isX = id < nX;
    const float* src; unsigned short* dst;
    if (isX) { src = X; dst = Xh; }
    else     { src = C; dst = Ch; id -= nX; }
    const float4* s4 = (const float4*)src;
    float4 a = s4[2*id], b = s4[2*id+1];
    float xs[8] = {a.x,a.y,a.z,a.w,b.x,b.y,b.z,b.w};
    ushort8 h;
    float ps = 0.f;
    #pragma unroll
    for (int i = 0; i < 8; ++i) {
        union { _Float16 f; unsigned short u; } cv;
        cv.f = (_Float16)xs[i];
        h[i] = cv.u;
        ps += xs[i]*xs[i];
    }
    ((ushort8*)dst)[id] = h;
    int t = threadIdx.x;
    if (isX) {   // block-uniform branch: per-block partial of sum(x^2)
        #pragma unroll
        for (int m = 1; m < 64; m <<= 1) ps += __shfl_xor(ps, m);
        if ((t & 63) == 0) red[t >> 6] = ps;
        __syncthreads();
        if (t == 0) xsq_part[blockIdx.x] = (red[0] + red[1]) + (red[2] + red[3]);
    } else {     // C rows: 32 consecutive threads cover one row (D=256 = 32*8)
        #pragma unroll
        for (int m = 1; m < 32; m <<= 1) ps += __shfl_xor(ps, m);
        if ((t & 31) == 0) c2[id >> 5] = ps;
    }
}

// ---------------- fp16 MFMA GEMM + fused top-2 argmin (m97-replica) ----------
// Grid (N/128, 4): blockIdx.y = kb picks a 1024-center K-slice (16 ct-tiles x 64).
// m97 structure at 12 waves/CU (m132: occupancy is the lever for this shape):
// stream BOTH A and B per K-step (BK=64 = two 32-depth sub-chunks -> 16 MFMA
// per wave per barrier, m97's ratio). LDS = A dbuf 32 KB + B dbuf 16 KB + c2
// slice 4 KB = 53248 B -> exactly 3 blocks/CU; __launch_bounds__(256,3) caps
// VGPR at ~170 (live set ~150: acc[2][4]=32 + top2=32 + frags + addr).
// 4 waves each own 32 rows; all waves share the 64-col B tile (LDS broadcast).
// One __syncthreads per K-step: the drain covers gload_lds issued one full
// K-step (~500+ cyc) earlier; 3 desynced blocks/CU hide each other's drains.
// c2 preloaded to LDS -> the ONLY in-loop VMEM is the 6 gload_lds per wave.
// Score = c2[col] - 2*dot (x2 omitted: row-constant, argmin-invariant).
// Output: cand[row][h], h = 2*kb + half: top-2 of cols [kb*1024+half*512, +512)
// (recheck merges any 8-subset partition of [0,4096) -- validated in r2/r3).
__global__ __launch_bounds__(256, 3) void mfma_assign(
        const unsigned short* __restrict__ Xh, const unsigned short* __restrict__ Ch,
        const float* __restrict__ c2g, float* __restrict__ cand)
{
    __shared__ __align__(16) unsigned short sA[2*8192];  // 32 KB: 2buf x (2dkk x 8q x 1KB)
    __shared__ __align__(16) unsigned short sB[2*4096];  // 16 KB: 2buf x (2dkk x 4p x 1KB)
    __shared__ float sC2[1024];                          //  4 KB

    const int t    = threadIdx.x;
    const int w    = t >> 6, l = t & 63;
    const int quad = l >> 4, lr = l & 15;
    const int rowbase = blockIdx.x * 128;
    const int kb   = blockIdx.y;                 // 0..3

    const int rl  = l >> 2;                      // staging local row (0..15)
    const int gsw = (l & 3) ^ ((l >> 3) & 3);    // swizzled depth-group to fetch

    // c2 slice for this kb -> LDS (256 thr x 16B = 4 KB)
    ((float4*)sC2)[t] = ((const float4*)(c2g + kb*1024))[t];

// stage K-step nk into buffer db: A 4 calls/wave + B 2 calls/wave
#define STAGE(nk, db) do {                                                     \
        _Pragma("unroll")                                                      \
        for (int m_ = 0; m_ < 4; ++m_) {                                       \
            int dkk_ = m_ & 1, q_ = 2*w + (m_ >> 1);                           \
            const unsigned short* gp_ = Xh + (size_t)(rowbase + q_*16 + rl)*D  \
                + (((nk) & 3)*2 + dkk_)*32 + gsw*8;                            \
            ld_lds16((char*)sA + (db)*16384 + dkk_*8192 + q_*1024, gp_);       \
        }                                                                      \
        _Pragma("unroll")                                                      \
        for (int dkk_ = 0; dkk_ < 2; ++dkk_) {                                 \
            const unsigned short* gp_ = Ch + (size_t)(kb*1024 + ((nk)>>2)*64   \
                + w*16 + rl)*D + (((nk) & 3)*2 + dkk_)*32 + gsw*8;             \
            ld_lds16((char*)sB + (db)*8192 + dkk_*4096 + w*1024, gp_);         \
        }                                                                      \
    } while (0)

    // prologue: K-step 0 into buf 0 (drained by the loop-top barrier at ks=0)
    STAGE(0, 0);

    const char* sAc = (const char*)sA;
    const char* sBc = (const char*)sB;
    const int slot   = quad ^ ((lr >> 1) & 3);   // 2-way banks = free
    const int sA_off = ((32*w + lr)*4 + slot)*16;   // + i*1024 + dkk*8192 + buf*16384
    const int sB_off = (lr*4 + slot)*16;            // + j*1024 + dkk*4096 + buf*8192

// one 32-depth sub-chunk: 2 A-frags x 4 B-frags = 8 MFMA
#define KSTEP(dkk) do {                                                        \
        const char* aB_ = sAc + buf*16384 + (dkk)*8192;                        \
        const char* bB_ = sBc + buf*8192  + (dkk)*4096;                        \
        half8 Af0 = *(const half8*)(aB_ + 0*1024 + sA_off);                    \
        half8 Af1 = *(const half8*)(aB_ + 1*1024 + sA_off);                    \
        half8 Bf0 = *(const half8*)(bB_ + 0*1024 + sB_off);                    \
        half8 Bf1 = *(const half8*)(bB_ + 1*1024 + sB_off);                    \
        half8 Bf2 = *(const half8*)(bB_ + 2*1024 + sB_off);                    \
        half8 Bf3 = *(const half8*)(bB_ + 3*1024 + sB_off);                    \
        acc[0][0] = mfma_f16(Af0, Bf0, acc[0][0]);                             \
        acc[1][0] = mfma_f16(Af1, Bf0, acc[1][0]);                             \
        acc[0][1] = mfma_f16(Af0, Bf1, acc[0][1]);                             \
        acc[1][1] = mfma_f16(Af1, Bf1, acc[1][1]);                             \
        acc[0][2] = mfma_f16(Af0, Bf2, acc[0][2]);                             \
        acc[1][2] = mfma_f16(Af1, Bf2, acc[1][2]);                             \
        acc[0][3] = mfma_f16(Af0, Bf3, acc[0][3]);                             \
        acc[1][3] = mfma_f16(Af1, Bf3, acc[1][3]);                             \
    } while (0)

// cross-lane (16 lr lanes) top-2 butterfly per owned row, write entry h, reinit
#define FLUSH(h) do {                                                          \
    _Pragma("unroll")                                                          \
    for (int i = 0; i < 2; ++i)                                                \
        _Pragma("unroll")                                                      \
        for (int r = 0; r < 4; ++r) {                                          \
            int st = 4*i + r;                                                  \
            float a1 = v1[st], a2 = v2[st]; int ax1 = x1[st], ax2 = x2s[st];   \
            _Pragma("unroll")                                                  \
            for (int m = 1; m < 16; m <<= 1) {                                 \
                float b1f = __shfl_xor(a1, m); int bx1 = __shfl_xor(ax1, m);   \
                float b2f = __shfl_xor(a2, m); int bx2 = __shfl_xor(ax2, m);   \
                bool tt = (b1f < a1) || (b1f == a1 && bx1 < ax1);              \
                float n1 = tt ? b1f : a1; int nx1 = tt ? bx1 : ax1;            \
                float w1 = tt ? a1 : b1f; int wx1 = tt ? ax1 : bx1;            \
                float w2 = tt ? b2f : a2; int wx2 = tt ? bx2 : ax2;            \
                bool uu = (w2 < w1) || (w2 == w1 && wx2 < wx1);                \
                a1 = n1; ax1 = nx1;                                            \
                a2 = uu ? w2 : w1; ax2 = uu ? wx2 : wx1;                       \
            }                                                                  \
            if (lr == 0) {                                                     \
                int row = rowbase + 32*w + 16*i + 4*quad + r;                  \
                float4 o; o.x = a1; o.y = __int_as_float(ax1);                 \
                o.z = a2; o.w = __int_as_float(ax2);                           \
                ((float4*)cand)[(size_t)row*8 + (h)] = o;                      \
            }                                                                  \
            v1[st] = FLT_MAX; v2[st] = FLT_MAX;                                \
            x1[st] = 0x7fffffff; x2s[st] = 0x7fffffff;                         \
        } } while (0)

    // per-lane running top-2 per owned row (8 rows: st = 4*i + r)
    float v1[8], v2[8]; int x1[8], x2s[8];
    #pragma unroll
    for (int i = 0; i < 8; ++i) { v1[i]=FLT_MAX; v2[i]=FLT_MAX; x1[i]=0x7fffffff; x2s[i]=0x7fffffff; }

    floatx4 acc[2][4];
    float c2v[4]; int jidx[4];
    int buf = 0;

    for (int ks = 0; ks < 64; ++ks) {            // ct = ks>>2, dk-pair = ks&3
        __syncthreads();    // drains K-step ks's staging (issued at ks-1) + frees buf^1

        if (ks < 63) STAGE(ks + 1, buf ^ 1);

        if ((ks & 3) == 0) {
            const int ct = ks >> 2;
            #pragma unroll
            for (int i = 0; i < 2; ++i)
                #pragma unroll
                for (int j = 0; j < 4; ++j) acc[i][j] = (floatx4)0.f;
            #pragma unroll
            for (int j = 0; j < 4; ++j) {
                int cc = ct*64 + 16*j + lr;
                c2v[j] = sC2[cc];                // LDS read (stable after 1st barrier)
                jidx[j] = kb*1024 + cc;
            }
        }

        KSTEP(0);
        KSTEP(1);

        if ((ks & 3) == 3) {
            // fused top-2 merge: rows st=4i+r (row=32w+16i+4quad+r), cols jidx[j]
            #pragma unroll
            for (int i = 0; i < 2; ++i)
                #pragma unroll
                for (int j = 0; j < 4; ++j)
                    #pragma unroll
                    for (int r = 0; r < 4; ++r) {
                        float s = fmaf(-2.f, acc[i][j][r], c2v[j]);
                        int st = 4*i + r;
                        bool cA = s < v1[st];
                        bool cB = s < v2[st];
                        float tv = cB ? s : v2[st]; int tx = cB ? jidx[j] : x2s[st];
                        v2[st] = cA ? v1[st] : tv;  x2s[st] = cA ? x1[st] : tx;
                        v1[st] = cA ? s : v1[st];   x1[st]  = cA ? jidx[j] : x1[st];
                    }
        }
        if (ks == 31) FLUSH(2*kb);               // first 512-col half done
        buf ^= 1;
    }
    FLUSH(2*kb + 1);                             // second half

#undef STAGE
#undef KSTEP
#undef FLUSH
}

// ------- margin-gated exact recheck + labels + histogram, 4 rows per wave ------
// Lanes split into 4 groups of 16; group g owns row 4*waverow+g. One butterfly
// serves all 4 rows. Certain groups (margin > 0.25) write immediately with no
// memory traffic; uncertain rows (rare) are handled whole-wave sequentially.
__global__ __launch_bounds__(256) void recheck_label(
        const float* __restrict__ X, const float* __restrict__ C,
        const float* __restrict__ c2, const float* __restrict__ cand,
        float* __restrict__ out_labels, int* __restrict__ labInt,
        int* __restrict__ cnt)
{
    int t = threadIdx.x, w = t >> 6, l = t & 63;
    int g  = l >> 4;                       // row-group within wave
    int lr = l & 15;
    int row0 = (blockIdx.x * 4 + w) * 4;   // 4 rows per wave
    int row  = row0 + g;

    // lane lr of group g holds candidate lr of its row
    float4 e = ((const float4*)cand)[(size_t)row*8 + (lr >> 1)];
    float s  = (lr & 1) ? e.z : e.x;
    int  idx = (lr & 1) ? __float_as_int(e.w) : __float_as_int(e.y);

    // top-2 butterfly within each 16-lane group (all lanes end with group result)
    float a1 = s, a2 = FLT_MAX; int ax1 = idx, ax2 = 0x7fffffff;
    #pragma unroll
    for (int m = 1; m < 16; m <<= 1) {
        float b1 = __shfl_xor(a1, m); int bx1 = __shfl_xor(ax1, m);
        float b2 = __shfl_xor(a2, m); int bx2 = __shfl_xor(ax2, m);
        bool tt = (b1 < a1) || (b1 == a1 && bx1 < ax1);
        float n1 = tt ? b1 : a1; int nx1 = tt ? bx1 : ax1;
        float w1 = tt ? a1 : b1; int wx1 = tt ? ax1 : bx1;
        float w2 = tt ? b2 : a2; int wx2 = tt ? bx2 : ax2;
        bool uu = (w2 < w1) || (w2 == w1 && wx2 < wx1);
        a1 = n1; ax1 = nx1;
        a2 = uu ? w2 : w1; ax2 = uu ? wx2 : wx1;
    }

    bool certain = (a2 - a1 > 0.25f);               // group-uniform
    unsigned long long certMask = __ballot(certain);

    // fast path: certain groups store now (no X/C traffic)
    if (certain && lr == 0) {
        out_labels[row] = (float)ax1;
        labInt[row] = ax1;
        atomicAdd(&cnt[ax1], 1);
    }

    // slow path: whole wave processes each uncertain row sequentially
    #pragma unroll
    for (int q = 0; q < 4; ++q) {
        if ((certMask >> (q*16)) & 1ull) continue;   // wave-uniform test
        int r = row0 + q;
        float sq  = __shfl(s,   q*16 + lr);          // group q's candidates -> lanes 0..15
        int   iq  = __shfl(idx, q*16 + lr);
        float gs1 = __shfl(a1,  q*16);

        float4 xv = ((const float4*)X)[(size_t)r*64 + l];
        float px = xv.x*xv.x + xv.y*xv.y + xv.z*xv.z + xv.w*xv.w;
        #pragma unroll
        for (int m = 1; m < 64; m <<= 1) px += __shfl_xor(px, m);

        bool active = (l < 16) && (sq <= gs1 + 0.25f);
        unsigned long long mask = __ballot(active);
        float best = FLT_MAX; int bi = 0x7fffffff;
        while (mask) {
            int k = __ffsll((long long)mask) - 1;
            mask &= mask - 1;
            int ck = __shfl(iq, k);
            float4 cv = ((const float4*)C)[(size_t)ck*64 + l];
            float pd = xv.x*cv.x + xv.y*cv.y + xv.z*cv.z + xv.w*cv.w;
            #pragma unroll
            for (int m = 1; m < 64; m <<= 1) pd += __shfl_xor(pd, m);
            float d2 = fmaf(-2.f, pd, px) + c2[ck];   // numpy's rounding order
            if (d2 < best || (d2 == best && ck < bi)) { best = d2; bi = ck; }
        }
        if (l == 0) {
            out_labels[r] = (float)bi;
            labInt[r] = bi;
            atomicAdd(&cnt[bi], 1);
        }
    }
}

// ---------------- exclusive prefix sum of the 4096-bin histogram -------------
__global__ void prefix_kernel(const int* __restrict__ cnt,
                              int* __restrict__ offs, int* __restrict__ cursor) {
    int l = threadIdx.x;                 // 64 lanes, 64 bins each
    int s = 0;
    #pragma unroll 8
    for (int i = 0; i < 64; ++i) s += cnt[l*64 + i];
    int inc = s;
    #pragma unroll
    for (int off = 1; off < 64; off <<= 1) {
        int u = __shfl_up(inc, off);
        if (l >= off) inc += u;
    }
    int run = inc - s;                   // exclusive lane base
    for (int i = 0; i < 64; ++i) {
        int k = l*64 + i;
        offs[k] = run; cursor[k] = run;
        run += cnt[k];
    }
}

// ---------------- bucket rows by label (one position atomic per row) ---------
__global__ void scatter_idx(const int* __restrict__ labInt,
                            int* __restrict__ cursor, int* __restrict__ sortedIdx) {
    int i = blockIdx.x * 256 + threadIdx.x;
    int lab = labInt[i];
    int pos = atomicAdd(&cursor[lab], 1);
    sortedIdx[pos] = i;
}

// -- atomic-free segment sum (block per center) + finalize + loss term store --
// loss = sum(x^2) [xsq_part] + sum_k (m_k*|c_k|^2 - 2*c_k.seg_k) [lossC, here]
__global__ __launch_bounds__(256) void center_update(
        const float* __restrict__ X, const float* __restrict__ C,
        const int* __restrict__ counts0, const int* __restrict__ cnt,
        const int* __restrict__ offs, const int* __restrict__ sortedIdx,
        float* __restrict__ lossC, float* __restrict__ out)
{
    __shared__ float red[4];
    int k = blockIdx.x, d = threadIdx.x;   // d = dim (D == 256 == blockDim)
    int start = offs[k], m = cnt[k];
    float acc = 0.f;
    int i = 0;
    for (; i + 4 <= m; i += 4) {
        int r0 = sortedIdx[start+i],   r1 = sortedIdx[start+i+1];
        int r2 = sortedIdx[start+i+2], r3 = sortedIdx[start+i+3];
        float a0 = X[(size_t)r0*D + d], a1 = X[(size_t)r1*D + d];
        float a2 = X[(size_t)r2*D + d], a3 = X[(size_t)r3*D + d];
        acc += (a0 + a1) + (a2 + a3);
    }
    for (; i < m; ++i) acc += X[(size_t)sortedIdx[start+i]*D + d];

    float cv = C[(size_t)k*D + d];
    float c0 = (float)counts0[k];
    out[N + (size_t)k*D + d] = (c0 * cv + acc) / (c0 + (float)m);
    if (d == 0) out[N + (size_t)K*D + k] = (float)(counts0[k] + m);

    // loss center-term: cv*(m*cv - 2*acc), reduced over d, plain store (no atomic)
    float lp = cv * fmaf((float)m, cv, -2.f*acc);
    #pragma unroll
    for (int s = 1; s < 64; s <<= 1) lp += __shfl_xor(lp, s);
    if ((d & 63) == 0) red[d >> 6] = lp;
    __syncthreads();
    if (d == 0) lossC[k] = (red[0] + red[1]) + (red[2] + red[3]);
}

// ---------------- final loss: reduce 8192 xsq partials + 4096 center terms ----
__global__ __launch_bounds__(256) void loss_final(
        const float* __restrict__ xsq_part, const float* __restrict__ lossC,
        float* __restrict__ out)
{
    __shared__ double red[4];
    int t = threadIdx.x;
    double s = 0.0;
    for (int i = t; i < 8192; i += 256) s += (double)xsq_part[i];
    for (int i = t; i < 4096; i += 256) s += (double)lossC[i];
    #pragma unroll
    for (int m = 1; m < 64; m <<= 1) s += __shfl_xor(s, m);
    if ((t & 63) == 0) red[t >> 6] = s;
    __syncthreads();
    if (t == 0)
        out[N + (size_t)K*D + K] = (float)(((red[0] + red[1]) + (red[2] + red[3])) / (double)N);
}

// ---------------- finalize (fallback path only) ----------------
__global__ void finalize_kernel(const float* __restrict__ C,
                                const int* __restrict__ counts0,
                                const float* __restrict__ seg,
                                const int* __restrict__ cnt,
                                const double* __restrict__ lossAcc,
                                float* __restrict__ out)
{
    int g = blockIdx.x * 256 + threadIdx.x;   // 0 .. K*D-1
    int k = g >> 8;                           // D = 256
    float c0 = (float)counts0[k];
    float m  = (float)cnt[k];
    out[N + g] = (c0 * C[g] + seg[g]) / (c0 + m);
    if (g < K) out[N + (size_t)K*D + g] = (float)(counts0[g] + cnt[g]);
    if (g == 0) out[N + (size_t)K*D + K] = (float)(lossAcc[0] / (double)N);
}

// ================= fallback (round-1 proven fp32 path, small ws) =============
__global__ __launch_bounds__(256, 2) void assign_fp32(
        const float* __restrict__ X, const float* __restrict__ C,
        const float* __restrict__ c2, float* __restrict__ out_labels,
        float* __restrict__ seg, int* __restrict__ cnt,
        double* __restrict__ lossAcc)
{
    constexpr int BM = 128, BN = 128, KD = 16;
    __shared__ float As[KD][BM];
    __shared__ float Bs[KD][BN];
    __shared__ float x2f[BM];
    __shared__ int   labs[BM];

    const int t  = threadIdx.x;
    const int tx = t & 15;
    const int ty = t >> 4;
    const int rowbase = blockIdx.x * BM;

    {
        int r  = t >> 1;
        int dh = (t & 1) * (D / 2);
        const float4* xr = (const float4*)(X + (size_t)(rowbase + r) * D + dh);
        float s = 0.f;
        #pragma unroll
        for (int i = 0; i < D / 8; ++i) {
            float4 v = xr[i];
            s += v.x*v.x + v.y*v.y + v.z*v.z + v.w*v.w;
        }
        s += __shfl_xor(s, 1);
        if ((t & 1) == 0) x2f[r] = s;
    }
    __syncthreads();

    float x2v[8];
    #pragma unroll
    for (int i = 0; i < 4; ++i) { x2v[i] = x2f[4*ty + i]; x2v[i+4] = x2f[64 + 4*ty + i]; }

    float rmv[8]; int rmi[8];
    #pragma unroll
    for (int i = 0; i < 8; ++i) { rmv[i] = FLT_MAX; rmi[i] = 0x7fffffff; }

    for (int ct = 0; ct < K / BN; ++ct) {
        float acc[8][8];
        #pragma unroll
        for (int i = 0; i < 8; ++i)
            #pragma unroll
            for (int j = 0; j < 8; ++j) acc[i][j] = 0.f;

        float c2f2[8];
        {
            float4 a = *(const float4*)(c2 + ct*BN + 4*tx);
            float4 b = *(const float4*)(c2 + ct*BN + 64 + 4*tx);
            c2f2[0]=a.x; c2f2[1]=a.y; c2f2[2]=a.z; c2f2[3]=a.w;
            c2f2[4]=b.x; c2f2[5]=b.y; c2f2[6]=b.z; c2f2[7]=b.w;
        }

        for (int dk = 0; dk < D / KD; ++dk) {
            #pragma unroll
            for (int i = 0; i < 2; ++i) {
                int f  = t + 256 * i;
                int r  = f >> 2;
                int dp = f & 3;
                float4 av = *(const float4*)(X + (size_t)(rowbase + r) * D + dk*KD + 4*dp);
                float4 bv = *(const float4*)(C + (size_t)(ct*BN + r) * D + dk*KD + 4*dp);
                As[4*dp+0][r]=av.x; As[4*dp+1][r]=av.y; As[4*dp+2][r]=av.z; As[4*dp+3][r]=av.w;
                Bs[4*dp+0][r]=bv.x; Bs[4*dp+1][r]=bv.y; Bs[4*dp+2][r]=bv.z; Bs[4*dp+3][r]=bv.w;
            }
            __syncthreads();
            #pragma unroll
            for (int kk = 0; kk < KD; ++kk) {
                float4 a0 = *(const float4*)&As[kk][4*ty];
                float4 a1 = *(const float4*)&As[kk][64 + 4*ty];
                float4 b0 = *(const float4*)&Bs[kk][4*tx];
                float4 b1 = *(const float4*)&Bs[kk][64 + 4*tx];
                float av[8] = {a0.x,a0.y,a0.z,a0.w,a1.x,a1.y,a1.z,a1.w};
                float bv[8] = {b0.x,b0.y,b0.z,b0.w,b1.x,b1.y,b1.z,b1.w};
                #pragma unroll
                for (int i = 0; i < 8; ++i)
                    #pragma unroll
                    for (int j = 0; j < 8; ++j)
                        acc[i][j] = fmaf(av[i], bv[j], acc[i][j]);
            }
            __syncthreads();
        }

        #pragma unroll
        for (int i = 0; i < 8; ++i) {
            float bv = FLT_MAX; int bi = 0x7fffffff;
            #pragma unroll
            for (int j = 0; j < 8; ++j) {
                int coll = (j < 4) ? (4*tx + j) : (64 + 4*tx + (j - 4));
                float v = fmaf(-2.f, acc[i][j], x2v[i]) + c2f2[j];
                int idx = ct * BN + coll;
                if (v < bv || (v == bv && idx < bi)) { bv = v; bi = idx; }
            }
            #pragma unroll
            for (int m = 1; m < 16; m <<= 1) {
                float ov = __shfl_xor(bv, m);
                int   oi = __shfl_xor(bi, m);
                if (ov < bv || (ov == bv && oi < bi)) { bv = ov; bi = oi; }
            }
            if (bv < rmv[i] || (bv == rmv[i] && bi < rmi[i])) { rmv[i] = bv; rmi[i] = bi; }
        }
    }

    if (tx == 0) {
        #pragma unroll
        for (int i = 0; i < 8; ++i) {
            int r = (i < 4) ? (4*ty + i) : (64 + 4*ty + (i - 4));
            labs[r] = rmi[i];
            out_labels[rowbase + r] = (float)rmi[i];
            atomicAdd(&cnt[rmi[i]], 1);
        }
    }
    __syncthreads();

    {
        int r   = t >> 1;
        int dh  = (t & 1) * (D / 2);
        int lab = labs[r];
        const float4* xr = (const float4*)(X + (size_t)(rowbase + r) * D + dh);
        const float4* cr = (const float4*)(C + (size_t)lab * D + dh);
        float* sp = seg + (size_t)lab * D + dh;
        float ls = 0.f;
        #pragma unroll 8
        for (int i = 0; i < D / 8; ++i) {
            float4 xv = xr[i];
            float4 cv = cr[i];
            atomicAdd(sp + 4*i + 0, xv.x);
            atomicAdd(sp + 4*i + 1, xv.y);
            atomicAdd(sp + 4*i + 2, xv.z);
            atomicAdd(sp + 4*i + 3, xv.w);
            float d0 = xv.x - cv.x, d1 = xv.y - cv.y;
            float d2 = xv.z - cv.z, d3 = xv.w - cv.w;
            ls += d0*d0 + d1*d1 + d2*d2 + d3*d3;
        }
        #pragma unroll
        for (int m = 1; m < 64; m <<= 1) ls += __shfl_xor(ls, m);
        if ((t & 63) == 0) atomicAdd(lossAcc, (double)ls);
    }
}

extern "C" void kernel_launch(void* const* d_in, const int* in_sizes, int n_in,
                              void* d_out, int out_size, void* d_ws, size_t ws_size,
                              hipStream_t stream) {
    const float* X       = (const float*)d_in[0];   // [N, D]
    const float* C       = (const float*)d_in[1];   // [K, D]
    const int*   counts0 = (const int*)d_in[2];     // [K]
    float* out = (float*)d_out;

    // workspace layout
    char* p = (char*)d_ws;
    float*  seg     = (float*)p;          p += (size_t)K * D * 4;   // 4 MB (fallback / sort scratch)
    int*    cnt     = (int*)p;            p += (size_t)K * 4;       // 16 KB
    float*  c2      = (float*)p;          p += (size_t)K * 4;       // 16 KB
    double* lossAcc = (double*)p;         p += 16;
    size_t zero_all = (size_t)(p - (char*)d_ws);
    float*  cand    = (float*)p;          p += (size_t)N * 32 * 4;  // 8 MB (16 cands/row)
    unsigned short* Xh = (unsigned short*)p; p += (size_t)N * D * 2; // 32 MB
    unsigned short* Ch = (unsigned short*)p; p += (size_t)K * D * 2; //  2 MB (row-major)
    float* xsq_part = (float*)p;          p += 8192 * 4;            // 32 KB
    float* lossC    = (float*)p;          p += (size_t)K * 4;       // 16 KB
    size_t need = (size_t)(p - (char*)d_ws);                        // ~46 MB

    // sort scratch reuses the seg region (mfma path never touches seg)
    int* labInt    = (int*)seg;                  // N ints
    int* sortedIdx = labInt + N;                 // N ints
    int* offs      = sortedIdx + N;              // K ints
    int* cursor    = offs + K;                   // K ints

    if (ws_size >= need) {
        hipMemsetAsync(cnt, 0, (size_t)K * 4, stream);  // histogram only
        convert_f16_both<<<(N*D/8 + K*D/8)/256, 256, 0, stream>>>(X, C, Xh, Ch, xsq_part, c2);
        mfma_assign<<<dim3(N/128, 4), 256, 0, stream>>>(Xh, Ch, c2, cand);
        recheck_label<<<N/16, 256, 0, stream>>>(X, C, c2, cand, out, labInt, cnt);
        prefix_kernel<<<1, 64, 0, stream>>>(cnt, offs, cursor);
        scatter_idx<<<N/256, 256, 0, stream>>>(labInt, cursor, sortedIdx);
        center_update<<<K, 256, 0, stream>>>(X, C, counts0, cnt, offs, sortedIdx, lossC, out);
        loss_final<<<1, 256, 0, stream>>>(xsq_part, lossC, out);
    } else {
        hipMemsetAsync(d_ws, 0, zero_all, stream);
        prep_c2<<<K, 64, 0, stream>>>(C, c2);
        assign_fp32<<<N/128, 256, 0, stream>>>(X, C, c2, out, seg, cnt, lossAcc);
        finalize_kernel<<<(K*D)/256, 256, 0, stream>>>(C, counts0, seg, cnt, lossAcc, out);
    }
}

// Round 5
// 588.398 us; speedup vs baseline: 1.1172x; 1.1079x over previous
//
#include <hip/hip_runtime.h>
#include <cfloat>
#include <cstdint>

// Problem constants (fixed by the reference: N=65536, D=256, K=4096)
constexpr int N  = 65536;
constexpr int D  = 256;
constexpr int K  = 4096;

typedef __attribute__((ext_vector_type(8))) _Float16 half8;          // fp16x8 MFMA frag
typedef __attribute__((ext_vector_type(8))) unsigned short ushort8;  // 16B vector
typedef __attribute__((ext_vector_type(4))) float floatx4;

__device__ __forceinline__ floatx4 mfma_f16(half8 a, half8 b, floatx4 c) {
    return __builtin_amdgcn_mfma_f32_16x16x32_f16(a, b, c, 0, 0, 0);
}

// async global->LDS, 16B per lane; LDS dest = uniform base + lane*16 (m97 semantics)
__device__ __forceinline__ void ld_lds16(void* lds, const void* g) {
    __builtin_amdgcn_global_load_lds(
        (const __attribute__((address_space(1))) unsigned int*)g,
        (__attribute__((address_space(3))) unsigned int*)lds, 16, 0, 0);
}

// ---------------- c2[k] = sum_d C[k][d]^2 (fallback path only) ----------------
__global__ void prep_c2(const float* __restrict__ C, float* __restrict__ c2) {
    int k = blockIdx.x;
    int l = threadIdx.x;
    const float4* row = (const float4*)(C + (size_t)k * D);
    float4 v = row[l];
    float s = v.x*v.x + v.y*v.y + v.z*v.z + v.w*v.w;
    #pragma unroll
    for (int m = 1; m < 64; m <<= 1) s += __shfl_xor(s, m);
    if (l == 0) c2[k] = s;
}

// -- fp32 -> fp16 (RTN), X and C in one launch; per-BLOCK sum(x^2) partials and
// fused c2 (sum of C row squares) -- no hot atomics anywhere. Ch is row-major.
__global__ void convert_f16_both(const float* __restrict__ X, const float* __restrict__ C,
                                 unsigned short* __restrict__ Xh,
                                 unsigned short* __restrict__ Ch,
                                 float* __restrict__ xsq_part,
                                 float* __restrict__ c2) {
    __shared__ float red[4];
    int id = blockIdx.x * 256 + threadIdx.x;
    const int nX = N * D / 8;                     // first 8192 blocks are pure X
    bool isX = id < nX;
    const float* src; unsigned short* dst;
    if (isX) { src = X; dst = Xh; }
    else     { src = C; dst = Ch; id -= nX; }
    const float4* s4 = (const float4*)src;
    float4 a = s4[2*id], b = s4[2*id+1];
    float xs[8] = {a.x,a.y,a.z,a.w,b.x,b.y,b.z,b.w};
    ushort8 h;
    float ps = 0.f;
    #pragma unroll
    for (int i = 0; i < 8; ++i) {
        union { _Float16 f; unsigned short u; } cv;
        cv.f = (_Float16)xs[i];
        h[i] = cv.u;
        ps += xs[i]*xs[i];
    }
    ((ushort8*)dst)[id] = h;
    int t = threadIdx.x;
    if (isX) {   // block-uniform branch: per-block partial of sum(x^2)
        #pragma unroll
        for (int m = 1; m < 64; m <<= 1) ps += __shfl_xor(ps, m);
        if ((t & 63) == 0) red[t >> 6] = ps;
        __syncthreads();
        if (t == 0) xsq_part[blockIdx.x] = (red[0] + red[1]) + (red[2] + red[3]);
    } else {     // C rows: 32 consecutive threads cover one row (D=256 = 32*8)
        #pragma unroll
        for (int m = 1; m < 32; m <<= 1) ps += __shfl_xor(ps, m);
        if ((t & 31) == 0) c2[id >> 5] = ps;
    }
}

// ---------------- fp16 MFMA GEMM + fused top-2 argmin (m97-replica) ----------
// Flat grid of 2048 blocks; bijective XCD swizzle (T1, panel-major):
//   sw = (bid%8)*256 + bid/8;  kb = sw&3;  panel = sw>>2.
// XCD c owns panels [64c, 64c+64), the 4 kb-siblings of a panel co-resident ->
// per-XCD hot set = 24 panels x 64KB A (1.5MB) + 2MB B + c2 ~= 3.5MB < 4MB L2.
// Fixes round-4's 843MB FETCH (A re-stage 16x missing L2 -> L3 latency stall).
// m97 structure at 12 waves/CU: stream BOTH A and B per K-step (BK=64 = two
// 32-depth sub-chunks -> 16 MFMA/wave/barrier). LDS = A dbuf 32KB + B dbuf
// 16KB + c2 4KB = 53248 B -> 3 blocks/CU. 4 waves x 32 rows; shared 64-col B.
// One __syncthreads per K-step; staging issued one K-step ahead (covers L2 hit).
// Score = c2[col] - 2*dot (x2 omitted: row-constant, argmin-invariant).
// Output: cand[row][h], h = 2*kb + half: top-2 of cols [kb*1024+half*512, +512).
__global__ __launch_bounds__(256, 3) void mfma_assign(
        const unsigned short* __restrict__ Xh, const unsigned short* __restrict__ Ch,
        const float* __restrict__ c2g, float* __restrict__ cand)
{
    __shared__ __align__(16) unsigned short sA[2*8192];  // 32 KB: 2buf x (2dkk x 8q x 1KB)
    __shared__ __align__(16) unsigned short sB[2*4096];  // 16 KB: 2buf x (2dkk x 4p x 1KB)
    __shared__ float sC2[1024];                          //  4 KB

    const int t    = threadIdx.x;
    const int w    = t >> 6, l = t & 63;
    const int quad = l >> 4, lr = l & 15;

    // bijective XCD swizzle (nwg=2048, nwg%8==0): panel-major within XCD
    const int bid   = blockIdx.x;
    const int sw    = (bid & 7) * 256 + (bid >> 3);
    const int kb    = sw & 3;                    // 0..3
    const int panel = sw >> 2;                   // 0..511
    const int rowbase = panel * 128;

    const int rl  = l >> 2;                      // staging local row (0..15)
    const int gsw = (l & 3) ^ ((l >> 3) & 3);    // swizzled depth-group to fetch

    // c2 slice for this kb -> LDS (256 thr x 16B = 4 KB)
    ((float4*)sC2)[t] = ((const float4*)(c2g + kb*1024))[t];

// stage K-step nk into buffer db: A 4 calls/wave + B 2 calls/wave
#define STAGE(nk, db) do {                                                     \
        _Pragma("unroll")                                                      \
        for (int m_ = 0; m_ < 4; ++m_) {                                       \
            int dkk_ = m_ & 1, q_ = 2*w + (m_ >> 1);                           \
            const unsigned short* gp_ = Xh + (size_t)(rowbase + q_*16 + rl)*D  \
                + (((nk) & 3)*2 + dkk_)*32 + gsw*8;                            \
            ld_lds16((char*)sA + (db)*16384 + dkk_*8192 + q_*1024, gp_);       \
        }                                                                      \
        _Pragma("unroll")                                                      \
        for (int dkk_ = 0; dkk_ < 2; ++dkk_) {                                 \
            const unsigned short* gp_ = Ch + (size_t)(kb*1024 + ((nk)>>2)*64   \
                + w*16 + rl)*D + (((nk) & 3)*2 + dkk_)*32 + gsw*8;             \
            ld_lds16((char*)sB + (db)*8192 + dkk_*4096 + w*1024, gp_);         \
        }                                                                      \
    } while (0)

    // prologue: K-step 0 into buf 0 (drained by the loop-top barrier at ks=0)
    STAGE(0, 0);

    const char* sAc = (const char*)sA;
    const char* sBc = (const char*)sB;
    const int slot   = quad ^ ((lr >> 1) & 3);   // 2-way banks = free
    const int sA_off = ((32*w + lr)*4 + slot)*16;   // + i*1024 + dkk*8192 + buf*16384
    const int sB_off = (lr*4 + slot)*16;            // + j*1024 + dkk*4096 + buf*8192

// one 32-depth sub-chunk: 2 A-frags x 4 B-frags = 8 MFMA
#define KSTEP(dkk) do {                                                        \
        const char* aB_ = sAc + buf*16384 + (dkk)*8192;                        \
        const char* bB_ = sBc + buf*8192  + (dkk)*4096;                        \
        half8 Af0 = *(const half8*)(aB_ + 0*1024 + sA_off);                    \
        half8 Af1 = *(const half8*)(aB_ + 1*1024 + sA_off);                    \
        half8 Bf0 = *(const half8*)(bB_ + 0*1024 + sB_off);                    \
        half8 Bf1 = *(const half8*)(bB_ + 1*1024 + sB_off);                    \
        half8 Bf2 = *(const half8*)(bB_ + 2*1024 + sB_off);                    \
        half8 Bf3 = *(const half8*)(bB_ + 3*1024 + sB_off);                    \
        acc[0][0] = mfma_f16(Af0, Bf0, acc[0][0]);                             \
        acc[1][0] = mfma_f16(Af1, Bf0, acc[1][0]);                             \
        acc[0][1] = mfma_f16(Af0, Bf1, acc[0][1]);                             \
        acc[1][1] = mfma_f16(Af1, Bf1, acc[1][1]);                             \
        acc[0][2] = mfma_f16(Af0, Bf2, acc[0][2]);                             \
        acc[1][2] = mfma_f16(Af1, Bf2, acc[1][2]);                             \
        acc[0][3] = mfma_f16(Af0, Bf3, acc[0][3]);                             \
        acc[1][3] = mfma_f16(Af1, Bf3, acc[1][3]);                             \
    } while (0)

// cross-lane (16 lr lanes) top-2 butterfly per owned row, write entry h, reinit
#define FLUSH(h) do {                                                          \
    _Pragma("unroll")                                                          \
    for (int i = 0; i < 2; ++i)                                                \
        _Pragma("unroll")                                                      \
        for (int r = 0; r < 4; ++r) {                                          \
            int st = 4*i + r;                                                  \
            float a1 = v1[st], a2 = v2[st]; int ax1 = x1[st], ax2 = x2s[st];   \
            _Pragma("unroll")                                                  \
            for (int m = 1; m < 16; m <<= 1) {                                 \
                float b1f = __shfl_xor(a1, m); int bx1 = __shfl_xor(ax1, m);   \
                float b2f = __shfl_xor(a2, m); int bx2 = __shfl_xor(ax2, m);   \
                bool tt = (b1f < a1) || (b1f == a1 && bx1 < ax1);              \
                float n1 = tt ? b1f : a1; int nx1 = tt ? bx1 : ax1;            \
                float w1 = tt ? a1 : b1f; int wx1 = tt ? ax1 : bx1;            \
                float w2 = tt ? b2f : a2; int wx2 = tt ? bx2 : ax2;            \
                bool uu = (w2 < w1) || (w2 == w1 && wx2 < wx1);                \
                a1 = n1; ax1 = nx1;                                            \
                a2 = uu ? w2 : w1; ax2 = uu ? wx2 : wx1;                       \
            }                                                                  \
            if (lr == 0) {                                                     \
                int row = rowbase + 32*w + 16*i + 4*quad + r;                  \
                float4 o; o.x = a1; o.y = __int_as_float(ax1);                 \
                o.z = a2; o.w = __int_as_float(ax2);                           \
                ((float4*)cand)[(size_t)row*8 + (h)] = o;                      \
            }                                                                  \
            v1[st] = FLT_MAX; v2[st] = FLT_MAX;                                \
            x1[st] = 0x7fffffff; x2s[st] = 0x7fffffff;                         \
        } } while (0)

    // per-lane running top-2 per owned row (8 rows: st = 4*i + r)
    float v1[8], v2[8]; int x1[8], x2s[8];
    #pragma unroll
    for (int i = 0; i < 8; ++i) { v1[i]=FLT_MAX; v2[i]=FLT_MAX; x1[i]=0x7fffffff; x2s[i]=0x7fffffff; }

    floatx4 acc[2][4];
    float c2v[4]; int jidx[4];
    int buf = 0;

    for (int ks = 0; ks < 64; ++ks) {            // ct = ks>>2, dk-pair = ks&3
        __syncthreads();    // drains K-step ks's staging (issued at ks-1) + frees buf^1

        if (ks < 63) STAGE(ks + 1, buf ^ 1);

        if ((ks & 3) == 0) {
            const int ct = ks >> 2;
            #pragma unroll
            for (int i = 0; i < 2; ++i)
                #pragma unroll
                for (int j = 0; j < 4; ++j) acc[i][j] = (floatx4)0.f;
            #pragma unroll
            for (int j = 0; j < 4; ++j) {
                int cc = ct*64 + 16*j + lr;
                c2v[j] = sC2[cc];                // LDS read (stable after 1st barrier)
                jidx[j] = kb*1024 + cc;
            }
        }

        KSTEP(0);
        KSTEP(1);

        if ((ks & 3) == 3) {
            // fused top-2 merge: rows st=4i+r (row=32w+16i+4quad+r), cols jidx[j]
            #pragma unroll
            for (int i = 0; i < 2; ++i)
                #pragma unroll
                for (int j = 0; j < 4; ++j)
                    #pragma unroll
                    for (int r = 0; r < 4; ++r) {
                        float s = fmaf(-2.f, acc[i][j][r], c2v[j]);
                        int st = 4*i + r;
                        bool cA = s < v1[st];
                        bool cB = s < v2[st];
                        float tv = cB ? s : v2[st]; int tx = cB ? jidx[j] : x2s[st];
                        v2[st] = cA ? v1[st] : tv;  x2s[st] = cA ? x1[st] : tx;
                        v1[st] = cA ? s : v1[st];   x1[st]  = cA ? jidx[j] : x1[st];
                    }
        }
        if (ks == 31) FLUSH(2*kb);               // first 512-col half done
        buf ^= 1;
    }
    FLUSH(2*kb + 1);                             // second half

#undef STAGE
#undef KSTEP
#undef FLUSH
}

// ------- margin-gated exact recheck + labels + histogram, 4 rows per wave ------
// Lanes split into 4 groups of 16; group g owns row 4*waverow+g. One butterfly
// serves all 4 rows. Certain groups (margin > 0.25) write immediately with no
// memory traffic; uncertain rows (rare) are handled whole-wave sequentially.
__global__ __launch_bounds__(256) void recheck_label(
        const float* __restrict__ X, const float* __restrict__ C,
        const float* __restrict__ c2, const float* __restrict__ cand,
        float* __restrict__ out_labels, int* __restrict__ labInt,
        int* __restrict__ cnt)
{
    int t = threadIdx.x, w = t >> 6, l = t & 63;
    int g  = l >> 4;                       // row-group within wave
    int lr = l & 15;
    int row0 = (blockIdx.x * 4 + w) * 4;   // 4 rows per wave
    int row  = row0 + g;

    // lane lr of group g holds candidate lr of its row
    float4 e = ((const float4*)cand)[(size_t)row*8 + (lr >> 1)];
    float s  = (lr & 1) ? e.z : e.x;
    int  idx = (lr & 1) ? __float_as_int(e.w) : __float_as_int(e.y);

    // top-2 butterfly within each 16-lane group (all lanes end with group result)
    float a1 = s, a2 = FLT_MAX; int ax1 = idx, ax2 = 0x7fffffff;
    #pragma unroll
    for (int m = 1; m < 16; m <<= 1) {
        float b1 = __shfl_xor(a1, m); int bx1 = __shfl_xor(ax1, m);
        float b2 = __shfl_xor(a2, m); int bx2 = __shfl_xor(ax2, m);
        bool tt = (b1 < a1) || (b1 == a1 && bx1 < ax1);
        float n1 = tt ? b1 : a1; int nx1 = tt ? bx1 : ax1;
        float w1 = tt ? a1 : b1; int wx1 = tt ? ax1 : bx1;
        float w2 = tt ? b2 : a2; int wx2 = tt ? bx2 : ax2;
        bool uu = (w2 < w1) || (w2 == w1 && wx2 < wx1);
        a1 = n1; ax1 = nx1;
        a2 = uu ? w2 : w1; ax2 = uu ? wx2 : wx1;
    }

    bool certain = (a2 - a1 > 0.25f);               // group-uniform
    unsigned long long certMask = __ballot(certain);

    // fast path: certain groups store now (no X/C traffic)
    if (certain && lr == 0) {
        out_labels[row] = (float)ax1;
        labInt[row] = ax1;
        atomicAdd(&cnt[ax1], 1);
    }

    // slow path: whole wave processes each uncertain row sequentially
    #pragma unroll
    for (int q = 0; q < 4; ++q) {
        if ((certMask >> (q*16)) & 1ull) continue;   // wave-uniform test
        int r = row0 + q;
        float sq  = __shfl(s,   q*16 + lr);          // group q's candidates -> lanes 0..15
        int   iq  = __shfl(idx, q*16 + lr);
        float gs1 = __shfl(a1,  q*16);

        float4 xv = ((const float4*)X)[(size_t)r*64 + l];
        float px = xv.x*xv.x + xv.y*xv.y + xv.z*xv.z + xv.w*xv.w;
        #pragma unroll
        for (int m = 1; m < 64; m <<= 1) px += __shfl_xor(px, m);

        bool active = (l < 16) && (sq <= gs1 + 0.25f);
        unsigned long long mask = __ballot(active);
        float best = FLT_MAX; int bi = 0x7fffffff;
        while (mask) {
            int k = __ffsll((long long)mask) - 1;
            mask &= mask - 1;
            int ck = __shfl(iq, k);
            float4 cv = ((const float4*)C)[(size_t)ck*64 + l];
            float pd = xv.x*cv.x + xv.y*cv.y + xv.z*cv.z + xv.w*cv.w;
            #pragma unroll
            for (int m = 1; m < 64; m <<= 1) pd += __shfl_xor(pd, m);
            float d2 = fmaf(-2.f, pd, px) + c2[ck];   // numpy's rounding order
            if (d2 < best || (d2 == best && ck < bi)) { best = d2; bi = ck; }
        }
        if (l == 0) {
            out_labels[r] = (float)bi;
            labInt[r] = bi;
            atomicAdd(&cnt[bi], 1);
        }
    }
}

// ---------------- exclusive prefix sum of the 4096-bin histogram -------------
__global__ void prefix_kernel(const int* __restrict__ cnt,
                              int* __restrict__ offs, int* __restrict__ cursor) {
    int l = threadIdx.x;                 // 64 lanes, 64 bins each
    int s = 0;
    #pragma unroll 8
    for (int i = 0; i < 64; ++i) s += cnt[l*64 + i];
    int inc = s;
    #pragma unroll
    for (int off = 1; off < 64; off <<= 1) {
        int u = __shfl_up(inc, off);
        if (l >= off) inc += u;
    }
    int run = inc - s;                   // exclusive lane base
    for (int i = 0; i < 64; ++i) {
        int k = l*64 + i;
        offs[k] = run; cursor[k] = run;
        run += cnt[k];
    }
}

// ---------------- bucket rows by label (one position atomic per row) ---------
__global__ void scatter_idx(const int* __restrict__ labInt,
                            int* __restrict__ cursor, int* __restrict__ sortedIdx) {
    int i = blockIdx.x * 256 + threadIdx.x;
    int lab = labInt[i];
    int pos = atomicAdd(&cursor[lab], 1);
    sortedIdx[pos] = i;
}

// -- atomic-free segment sum (block per center) + finalize + loss term store --
// loss = sum(x^2) [xsq_part] + sum_k (m_k*|c_k|^2 - 2*c_k.seg_k) [lossC, here]
__global__ __launch_bounds__(256) void center_update(
        const float* __restrict__ X, const float* __restrict__ C,
        const int* __restrict__ counts0, const int* __restrict__ cnt,
        const int* __restrict__ offs, const int* __restrict__ sortedIdx,
        float* __restrict__ lossC, float* __restrict__ out)
{
    __shared__ float red[4];
    int k = blockIdx.x, d = threadIdx.x;   // d = dim (D == 256 == blockDim)
    int start = offs[k], m = cnt[k];
    float acc = 0.f;
    int i = 0;
    for (; i + 4 <= m; i += 4) {
        int r0 = sortedIdx[start+i],   r1 = sortedIdx[start+i+1];
        int r2 = sortedIdx[start+i+2], r3 = sortedIdx[start+i+3];
        float a0 = X[(size_t)r0*D + d], a1 = X[(size_t)r1*D + d];
        float a2 = X[(size_t)r2*D + d], a3 = X[(size_t)r3*D + d];
        acc += (a0 + a1) + (a2 + a3);
    }
    for (; i < m; ++i) acc += X[(size_t)sortedIdx[start+i]*D + d];

    float cv = C[(size_t)k*D + d];
    float c0 = (float)counts0[k];
    out[N + (size_t)k*D + d] = (c0 * cv + acc) / (c0 + (float)m);
    if (d == 0) out[N + (size_t)K*D + k] = (float)(counts0[k] + m);

    // loss center-term: cv*(m*cv - 2*acc), reduced over d, plain store (no atomic)
    float lp = cv * fmaf((float)m, cv, -2.f*acc);
    #pragma unroll
    for (int s = 1; s < 64; s <<= 1) lp += __shfl_xor(lp, s);
    if ((d & 63) == 0) red[d >> 6] = lp;
    __syncthreads();
    if (d == 0) lossC[k] = (red[0] + red[1]) + (red[2] + red[3]);
}

// ---------------- final loss: reduce 8192 xsq partials + 4096 center terms ----
__global__ __launch_bounds__(256) void loss_final(
        const float* __restrict__ xsq_part, const float* __restrict__ lossC,
        float* __restrict__ out)
{
    __shared__ double red[4];
    int t = threadIdx.x;
    double s = 0.0;
    for (int i = t; i < 8192; i += 256) s += (double)xsq_part[i];
    for (int i = t; i < 4096; i += 256) s += (double)lossC[i];
    #pragma unroll
    for (int m = 1; m < 64; m <<= 1) s += __shfl_xor(s, m);
    if ((t & 63) == 0) red[t >> 6] = s;
    __syncthreads();
    if (t == 0)
        out[N + (size_t)K*D + K] = (float)(((red[0] + red[1]) + (red[2] + red[3])) / (double)N);
}

// ---------------- finalize (fallback path only) ----------------
__global__ void finalize_kernel(const float* __restrict__ C,
                                const int* __restrict__ counts0,
                                const float* __restrict__ seg,
                                const int* __restrict__ cnt,
                                const double* __restrict__ lossAcc,
                                float* __restrict__ out)
{
    int g = blockIdx.x * 256 + threadIdx.x;   // 0 .. K*D-1
    int k = g >> 8;                           // D = 256
    float c0 = (float)counts0[k];
    float m  = (float)cnt[k];
    out[N + g] = (c0 * C[g] + seg[g]) / (c0 + m);
    if (g < K) out[N + (size_t)K*D + g] = (float)(counts0[g] + cnt[g]);
    if (g == 0) out[N + (size_t)K*D + K] = (float)(lossAcc[0] / (double)N);
}

// ================= fallback (round-1 proven fp32 path, small ws) =============
__global__ __launch_bounds__(256, 2) void assign_fp32(
        const float* __restrict__ X, const float* __restrict__ C,
        const float* __restrict__ c2, float* __restrict__ out_labels,
        float* __restrict__ seg, int* __restrict__ cnt,
        double* __restrict__ lossAcc)
{
    constexpr int BM = 128, BN = 128, KD = 16;
    __shared__ float As[KD][BM];
    __shared__ float Bs[KD][BN];
    __shared__ float x2f[BM];
    __shared__ int   labs[BM];

    const int t  = threadIdx.x;
    const int tx = t & 15;
    const int ty = t >> 4;
    const int rowbase = blockIdx.x * BM;

    {
        int r  = t >> 1;
        int dh = (t & 1) * (D / 2);
        const float4* xr = (const float4*)(X + (size_t)(rowbase + r) * D + dh);
        float s = 0.f;
        #pragma unroll
        for (int i = 0; i < D / 8; ++i) {
            float4 v = xr[i];
            s += v.x*v.x + v.y*v.y + v.z*v.z + v.w*v.w;
        }
        s += __shfl_xor(s, 1);
        if ((t & 1) == 0) x2f[r] = s;
    }
    __syncthreads();

    float x2v[8];
    #pragma unroll
    for (int i = 0; i < 4; ++i) { x2v[i] = x2f[4*ty + i]; x2v[i+4] = x2f[64 + 4*ty + i]; }

    float rmv[8]; int rmi[8];
    #pragma unroll
    for (int i = 0; i < 8; ++i) { rmv[i] = FLT_MAX; rmi[i] = 0x7fffffff; }

    for (int ct = 0; ct < K / BN; ++ct) {
        float acc[8][8];
        #pragma unroll
        for (int i = 0; i < 8; ++i)
            #pragma unroll
            for (int j = 0; j < 8; ++j) acc[i][j] = 0.f;

        float c2f2[8];
        {
            float4 a = *(const float4*)(c2 + ct*BN + 4*tx);
            float4 b = *(const float4*)(c2 + ct*BN + 64 + 4*tx);
            c2f2[0]=a.x; c2f2[1]=a.y; c2f2[2]=a.z; c2f2[3]=a.w;
            c2f2[4]=b.x; c2f2[5]=b.y; c2f2[6]=b.z; c2f2[7]=b.w;
        }

        for (int dk = 0; dk < D / KD; ++dk) {
            #pragma unroll
            for (int i = 0; i < 2; ++i) {
                int f  = t + 256 * i;
                int r  = f >> 2;
                int dp = f & 3;
                float4 av = *(const float4*)(X + (size_t)(rowbase + r) * D + dk*KD + 4*dp);
                float4 bv = *(const float4*)(C + (size_t)(ct*BN + r) * D + dk*KD + 4*dp);
                As[4*dp+0][r]=av.x; As[4*dp+1][r]=av.y; As[4*dp+2][r]=av.z; As[4*dp+3][r]=av.w;
                Bs[4*dp+0][r]=bv.x; Bs[4*dp+1][r]=bv.y; Bs[4*dp+2][r]=bv.z; Bs[4*dp+3][r]=bv.w;
            }
            __syncthreads();
            #pragma unroll
            for (int kk = 0; kk < KD; ++kk) {
                float4 a0 = *(const float4*)&As[kk][4*ty];
                float4 a1 = *(const float4*)&As[kk][64 + 4*ty];
                float4 b0 = *(const float4*)&Bs[kk][4*tx];
                float4 b1 = *(const float4*)&Bs[kk][64 + 4*tx];
                float av[8] = {a0.x,a0.y,a0.z,a0.w,a1.x,a1.y,a1.z,a1.w};
                float bv[8] = {b0.x,b0.y,b0.z,b0.w,b1.x,b1.y,b1.z,b1.w};
                #pragma unroll
                for (int i = 0; i < 8; ++i)
                    #pragma unroll
                    for (int j = 0; j < 8; ++j)
                        acc[i][j] = fmaf(av[i], bv[j], acc[i][j]);
            }
            __syncthreads();
        }

        #pragma unroll
        for (int i = 0; i < 8; ++i) {
            float bv = FLT_MAX; int bi = 0x7fffffff;
            #pragma unroll
            for (int j = 0; j < 8; ++j) {
                int coll = (j < 4) ? (4*tx + j) : (64 + 4*tx + (j - 4));
                float v = fmaf(-2.f, acc[i][j], x2v[i]) + c2f2[j];
                int idx = ct * BN + coll;
                if (v < bv || (v == bv && idx < bi)) { bv = v; bi = idx; }
            }
            #pragma unroll
            for (int m = 1; m < 16; m <<= 1) {
                float ov = __shfl_xor(bv, m);
                int   oi = __shfl_xor(bi, m);
                if (ov < bv || (ov == bv && oi < bi)) { bv = ov; bi = oi; }
            }
            if (bv < rmv[i] || (bv == rmv[i] && bi < rmi[i])) { rmv[i] = bv; rmi[i] = bi; }
        }
    }

    if (tx == 0) {
        #pragma unroll
        for (int i = 0; i < 8; ++i) {
            int r = (i < 4) ? (4*ty + i) : (64 + 4*ty + (i - 4));
            labs[r] = rmi[i];
            out_labels[rowbase + r] = (float)rmi[i];
            atomicAdd(&cnt[rmi[i]], 1);
        }
    }
    __syncthreads();

    {
        int r   = t >> 1;
        int dh  = (t & 1) * (D / 2);
        int lab = labs[r];
        const float4* xr = (const float4*)(X + (size_t)(rowbase + r) * D + dh);
        const float4* cr = (const float4*)(C + (size_t)lab * D + dh);
        float* sp = seg + (size_t)lab * D + dh;
        float ls = 0.f;
        #pragma unroll 8
        for (int i = 0; i < D / 8; ++i) {
            float4 xv = xr[i];
            float4 cv = cr[i];
            atomicAdd(sp + 4*i + 0, xv.x);
            atomicAdd(sp + 4*i + 1, xv.y);
            atomicAdd(sp + 4*i + 2, xv.z);
            atomicAdd(sp + 4*i + 3, xv.w);
            float d0 = xv.x - cv.x, d1 = xv.y - cv.y;
            float d2 = xv.z - cv.z, d3 = xv.w - cv.w;
            ls += d0*d0 + d1*d1 + d2*d2 + d3*d3;
        }
        #pragma unroll
        for (int m = 1; m < 64; m <<= 1) ls += __shfl_xor(ls, m);
        if ((t & 63) == 0) atomicAdd(lossAcc, (double)ls);
    }
}

extern "C" void kernel_launch(void* const* d_in, const int* in_sizes, int n_in,
                              void* d_out, int out_size, void* d_ws, size_t ws_size,
                              hipStream_t stream) {
    const float* X       = (const float*)d_in[0];   // [N, D]
    const float* C       = (const float*)d_in[1];   // [K, D]
    const int*   counts0 = (const int*)d_in[2];     // [K]
    float* out = (float*)d_out;

    // workspace layout
    char* p = (char*)d_ws;
    float*  seg     = (float*)p;          p += (size_t)K * D * 4;   // 4 MB (fallback / sort scratch)
    int*    cnt     = (int*)p;            p += (size_t)K * 4;       // 16 KB
    float*  c2      = (float*)p;          p += (size_t)K * 4;       // 16 KB
    double* lossAcc = (double*)p;         p += 16;
    size_t zero_all = (size_t)(p - (char*)d_ws);
    float*  cand    = (float*)p;          p += (size_t)N * 32 * 4;  // 8 MB (16 cands/row)
    unsigned short* Xh = (unsigned short*)p; p += (size_t)N * D * 2; // 32 MB
    unsigned short* Ch = (unsigned short*)p; p += (size_t)K * D * 2; //  2 MB (row-major)
    float* xsq_part = (float*)p;          p += 8192 * 4;            // 32 KB
    float* lossC    = (float*)p;          p += (size_t)K * 4;       // 16 KB
    size_t need = (size_t)(p - (char*)d_ws);                        // ~46 MB

    // sort scratch reuses the seg region (mfma path never touches seg)
    int* labInt    = (int*)seg;                  // N ints
    int* sortedIdx = labInt + N;                 // N ints
    int* offs      = sortedIdx + N;              // K ints
    int* cursor    = offs + K;                   // K ints

    if (ws_size >= need) {
        hipMemsetAsync(cnt, 0, (size_t)K * 4, stream);  // histogram only
        convert_f16_both<<<(N*D/8 + K*D/8)/256, 256, 0, stream>>>(X, C, Xh, Ch, xsq_part, c2);
        mfma_assign<<<2048, 256, 0, stream>>>(Xh, Ch, c2, cand);
        recheck_label<<<N/16, 256, 0, stream>>>(X, C, c2, cand, out, labInt, cnt);
        prefix_kernel<<<1, 64, 0, stream>>>(cnt, offs, cursor);
        scatter_idx<<<N/256, 256, 0, stream>>>(labInt, cursor, sortedIdx);
        center_update<<<K, 256, 0, stream>>>(X, C, counts0, cnt, offs, sortedIdx, lossC, out);
        loss_final<<<1, 256, 0, stream>>>(xsq_part, lossC, out);
    } else {
        hipMemsetAsync(d_ws, 0, zero_all, stream);
        prep_c2<<<K, 64, 0, stream>>>(C, c2);
        assign_fp32<<<N/128, 256, 0, stream>>>(X, C, c2, out, seg, cnt, lossAcc);
        finalize_kernel<<<(K*D)/256, 256, 0, stream>>>(C, counts0, seg, cnt, lossAcc, out);
    }
}